// Round 1
// baseline (2926.272 us; speedup 1.0000x reference)
//
#include <hip/hip_runtime.h>
#include <hip/hip_bf16.h>
#include <math.h>

namespace {

constexpr int B_ = 2, S_ = 2048, D_ = 512, H_ = 8, HD_ = 64, K_ = 31,
              FF_ = 2048, G_ = 4, E_ = 2;
constexpr int N_ = B_ * S_;
constexpr float EPS_ = 1e-6f;
// padded slot capacity: 4096 + 4*63 rounded up to 68 tiles of 64
constexpr int PADCAP_ = 68 * 64;  // 4352

__device__ __forceinline__ float gelu_f(float x) {
  const float c = 0.7978845608028654f;  // sqrt(2/pi)
  return 0.5f * x * (1.0f + tanhf(c * (x + 0.044715f * x * x * x)));
}

// ---------------- LayerNorm: one block per row, 256 threads, 2 elem/thread ---
__global__ __launch_bounds__(256) void ln_kernel(
    const float* __restrict__ in, float* __restrict__ out,
    const float* __restrict__ scale, const float* __restrict__ bias) {
  int row = blockIdx.x;
  const float* xr = in + (size_t)row * D_;
  int t = threadIdx.x;
  float v0 = xr[t], v1 = xr[t + 256];
  float s = v0 + v1, sq = v0 * v0 + v1 * v1;
  for (int o = 32; o > 0; o >>= 1) {
    s += __shfl_down(s, o);
    sq += __shfl_down(sq, o);
  }
  __shared__ float sm[8];
  __shared__ float mr[2];
  int lane = t & 63, wid = t >> 6;
  if (lane == 0) { sm[wid] = s; sm[wid + 4] = sq; }
  __syncthreads();
  if (t == 0) {
    float ts = sm[0] + sm[1] + sm[2] + sm[3];
    float tq = sm[4] + sm[5] + sm[6] + sm[7];
    float m = ts / D_;
    float var = tq / D_ - m * m;
    mr[0] = m;
    mr[1] = rsqrtf(var + EPS_);
  }
  __syncthreads();
  float m = mr[0], rs = mr[1];
  float* orow = out + (size_t)row * D_;
  orow[t] = (v0 - m) * rs * scale[t] + bias[t];
  orow[t + 256] = (v1 - m) * rs * scale[t + 256] + bias[t + 256];
}

// ------------- shared 64x64 fp32 tile compute: As/Bs stored [16][68] ---------
__device__ __forceinline__ void mm_tile(const float (*As)[68], const float (*Bs)[68],
                                        int ty, int tx, float acc[4][4]) {
#pragma unroll
  for (int kk = 0; kk < 16; ++kk) {
    float4 av = *(const float4*)&As[kk][ty * 4];
    float4 bv = *(const float4*)&Bs[kk][tx * 4];
    float a[4] = {av.x, av.y, av.z, av.w};
    float b[4] = {bv.x, bv.y, bv.z, bv.w};
#pragma unroll
    for (int i = 0; i < 4; ++i)
#pragma unroll
      for (int j = 0; j < 4; ++j) acc[i][j] += a[i] * b[j];
  }
}

// ---------------- Conv1d(SAME, K=31) + bias + gelu + residual ----------------
// out[n,dout] = gelu( sum_{k,din} h[n+k-15, din] * ck[k,din,dout] + cb ) + x[n]
__global__ __launch_bounds__(256) void conv_kernel(
    const float* __restrict__ h, const float* __restrict__ ck,
    const float* __restrict__ cb, const float* __restrict__ xres,
    float* __restrict__ out) {
  __shared__ __align__(16) float As[16][68];
  __shared__ __align__(16) float Bs[16][68];
  int tm = blockIdx.x, tn = blockIdx.y;
  int tid = threadIdx.x, tx = tid & 15, ty = tid >> 4;
  float acc[4][4] = {};
  int row0 = tm * 64;
  int b = row0 / S_;
  int s0 = row0 - b * S_;
  for (int k = 0; k < K_; ++k) {
    int shift = k - 15;
    const float* Wk = ck + (size_t)k * D_ * D_ + tn * 64;
    for (int d0 = 0; d0 < D_; d0 += 16) {
#pragma unroll
      for (int i = 0; i < 4; ++i) {
        int e = i * 256 + tid;
        int r = e >> 4, c = e & 15;
        int s = s0 + r + shift;
        float val = 0.f;
        if (s >= 0 && s < S_) val = h[(size_t)(b * S_ + s) * D_ + d0 + c];
        As[c][r] = val;  // transposed store: [k][token]
      }
#pragma unroll
      for (int i = 0; i < 4; ++i) {
        int e = i * 256 + tid;
        int r = e >> 6, c = e & 63;
        Bs[r][c] = Wk[(size_t)(d0 + r) * D_ + c];
      }
      __syncthreads();
      mm_tile(As, Bs, ty, tx, acc);
      __syncthreads();
    }
  }
#pragma unroll
  for (int i = 0; i < 4; ++i) {
    int n = row0 + ty * 4 + i;
#pragma unroll
    for (int j = 0; j < 4; ++j) {
      int d = tn * 64 + tx * 4 + j;
      float v = acc[i][j] + cb[d];
      out[(size_t)n * D_ + d] = gelu_f(v) + xres[(size_t)n * D_ + d];
    }
  }
}

// ---------------- generic GEMM + bias: C[M,N] = A[M,K]*W[K,N] + bias ---------
__global__ __launch_bounds__(256) void gemm_bias_kernel(
    const float* __restrict__ A, const float* __restrict__ W,
    const float* __restrict__ bias, float* __restrict__ C,
    int M, int Kd, int Nd) {
  __shared__ __align__(16) float As[16][68];
  __shared__ __align__(16) float Bs[16][68];
  int tm = blockIdx.x, tn = blockIdx.y;
  int tid = threadIdx.x, tx = tid & 15, ty = tid >> 4;
  float acc[4][4] = {};
  for (int k0 = 0; k0 < Kd; k0 += 16) {
#pragma unroll
    for (int i = 0; i < 4; ++i) {
      int e = i * 256 + tid;
      int r = e >> 4, c = e & 15;
      As[c][r] = A[(size_t)(tm * 64 + r) * Kd + k0 + c];
    }
#pragma unroll
    for (int i = 0; i < 4; ++i) {
      int e = i * 256 + tid;
      int r = e >> 6, c = e & 63;
      Bs[r][c] = W[(size_t)(k0 + r) * Nd + tn * 64 + c];
    }
    __syncthreads();
    mm_tile(As, Bs, ty, tx, acc);
    __syncthreads();
  }
#pragma unroll
  for (int i = 0; i < 4; ++i) {
    int n = tm * 64 + ty * 4 + i;
#pragma unroll
    for (int j = 0; j < 4; ++j) {
      int d = tn * 64 + tx * 4 + j;
      C[(size_t)n * Nd + d] = acc[i][j] + bias[d];
    }
  }
}

// ----- WO projection + bias + residual; writes x2 to both d_out and bufB -----
__global__ __launch_bounds__(256) void gemm_wo_kernel(
    const float* __restrict__ A, const float* __restrict__ W,
    const float* __restrict__ bias, const float* __restrict__ res,
    float* __restrict__ out0, float* __restrict__ out1) {
  __shared__ __align__(16) float As[16][68];
  __shared__ __align__(16) float Bs[16][68];
  int tm = blockIdx.x, tn = blockIdx.y;
  int tid = threadIdx.x, tx = tid & 15, ty = tid >> 4;
  float acc[4][4] = {};
  for (int k0 = 0; k0 < D_; k0 += 16) {
#pragma unroll
    for (int i = 0; i < 4; ++i) {
      int e = i * 256 + tid;
      int r = e >> 4, c = e & 15;
      As[c][r] = A[(size_t)(tm * 64 + r) * D_ + k0 + c];
    }
#pragma unroll
    for (int i = 0; i < 4; ++i) {
      int e = i * 256 + tid;
      int r = e >> 6, c = e & 63;
      Bs[r][c] = W[(size_t)(k0 + r) * D_ + tn * 64 + c];
    }
    __syncthreads();
    mm_tile(As, Bs, ty, tx, acc);
    __syncthreads();
  }
#pragma unroll
  for (int i = 0; i < 4; ++i) {
    int n = tm * 64 + ty * 4 + i;
#pragma unroll
    for (int j = 0; j < 4; ++j) {
      int d = tn * 64 + tx * 4 + j;
      float v = acc[i][j] + bias[d] + res[(size_t)n * D_ + d];
      out0[(size_t)n * D_ + d] = v;
      out1[(size_t)n * D_ + d] = v;
    }
  }
}

// ---------------- flash attention: 32 q-rows per block, 64-key tiles ---------
__global__ __launch_bounds__(256) void attn_kernel(
    const float* __restrict__ q, const float* __restrict__ k,
    const float* __restrict__ v, float* __restrict__ o) {
  constexpr int QT = 32, KT = 64;
  __shared__ float Qs[QT][HD_];
  __shared__ float Ks[KT][HD_ + 1];
  __shared__ float Vs[KT][HD_ + 1];
  __shared__ float Ps[QT][KT + 1];
  __shared__ float Ms[QT], Ls[QT];
  int qt = blockIdx.x, h = blockIdx.y, b = blockIdx.z;
  int tid = threadIdx.x;
  int r = tid >> 3;    // 0..31 q-row
  int gsub = tid & 7;  // 8 lanes per row
  const float scale = 0.125f;  // 1/sqrt(64)
#pragma unroll
  for (int i = 0; i < 8; ++i) {
    int e = i * 256 + tid;
    int rr = e >> 6, d = e & 63;
    Qs[rr][d] = q[(size_t)(b * S_ + qt * QT + rr) * D_ + h * HD_ + d] * scale;
  }
  float oreg[8] = {};
  if (tid < QT) { Ms[tid] = -INFINITY; Ls[tid] = 0.f; }
  __syncthreads();
  for (int kt = 0; kt < S_ / KT; ++kt) {
#pragma unroll
    for (int i = 0; i < 16; ++i) {
      int e = i * 256 + tid;
      int j = e >> 6, d = e & 63;
      size_t src = (size_t)(b * S_ + kt * KT + j) * D_ + h * HD_ + d;
      Ks[j][d] = k[src];
      Vs[j][d] = v[src];
    }
    __syncthreads();
    // scores for keys gsub*8 .. gsub*8+7
    float sc[8];
#pragma unroll
    for (int jj = 0; jj < 8; ++jj) {
      int j = gsub * 8 + jj;
      float acc = 0.f;
#pragma unroll
      for (int d = 0; d < HD_; ++d) acc += Qs[r][d] * Ks[j][d];
      sc[jj] = acc;
    }
    float mx = sc[0];
#pragma unroll
    for (int jj = 1; jj < 8; ++jj) mx = fmaxf(mx, sc[jj]);
    for (int o_ = 1; o_ < 8; o_ <<= 1) mx = fmaxf(mx, __shfl_xor(mx, o_));
    float mold = Ms[r];                 // same-wave lockstep: read before write
    float mnew = fmaxf(mold, mx);
    float sum = 0.f;
#pragma unroll
    for (int jj = 0; jj < 8; ++jj) {
      float p = __expf(sc[jj] - mnew);
      Ps[r][gsub * 8 + jj] = p;
      sum += p;
    }
    for (int o_ = 1; o_ < 8; o_ <<= 1) sum += __shfl_xor(sum, o_);
    float corr = __expf(mold - mnew);   // 0 when mold == -inf
    if (gsub == 0) {
      Ms[r] = mnew;
      Ls[r] = Ls[r] * corr + sum;
    }
    // o update: all Ps[r][*] written by this row's lanes (same wave, lockstep)
#pragma unroll
    for (int dd = 0; dd < 8; ++dd) oreg[dd] *= corr;
    for (int j = 0; j < KT; ++j) {
      float p = Ps[r][j];
#pragma unroll
      for (int dd = 0; dd < 8; ++dd) oreg[dd] += p * Vs[j][gsub * 8 + dd];
    }
    __syncthreads();
  }
  float inv = 1.f / Ls[r];
#pragma unroll
  for (int dd = 0; dd < 8; ++dd)
    o[(size_t)(b * S_ + qt * QT + r) * D_ + h * HD_ + gsub * 8 + dd] =
        oreg[dd] * inv;
}

// ---------------- MoE bucketing: group tokens, pad each group to 64 ----------
__global__ __launch_bounds__(1024) void bucket_kernel(
    const int* __restrict__ gid, int* __restrict__ list, int* __restrict__ poff) {
  __shared__ int cnt[G_], start[G_ + 1], cur[G_];
  int t = threadIdx.x;
  if (t < G_) cnt[t] = 0;
  __syncthreads();
  for (int i = t; i < N_; i += 1024) atomicAdd(&cnt[gid[i]], 1);
  __syncthreads();
  if (t == 0) {
    int off = 0;
    for (int g = 0; g < G_; ++g) {
      start[g] = off;
      cur[g] = off;
      off += (cnt[g] + 63) & ~63;
    }
    start[G_] = off;
    for (int g = 0; g <= G_; ++g) poff[g] = start[g];
  }
  __syncthreads();
  for (int i = t; i < PADCAP_; i += 1024) list[i] = -1;
  __syncthreads();
  for (int i = t; i < N_; i += 1024) {
    int g = gid[i];
    int p = atomicAdd(&cur[g], 1);
    list[p] = i;
  }
}

// ---------------- MoE FF1: hid[slot,f] = gelu(x2[tok]*w1[g,e] + b1) ----------
__global__ __launch_bounds__(256) void ff1_kernel(
    const float* __restrict__ X, const float* __restrict__ w1,
    const float* __restrict__ b1, const int* __restrict__ list,
    const int* __restrict__ poff, int e, float* __restrict__ hid) {
  __shared__ __align__(16) float As[16][68];
  __shared__ __align__(16) float Bs[16][68];
  __shared__ int toks[64];
  __shared__ int gsh;
  int tm = blockIdx.x, tn = blockIdx.y;
  int slot0 = tm * 64;
  if (slot0 >= poff[G_]) return;
  int tid = threadIdx.x, tx = tid & 15, ty = tid >> 4;
  if (tid < 64) toks[tid] = list[slot0 + tid];
  if (tid == 0) {
    int g = 0;
    while (slot0 >= poff[g + 1]) ++g;
    gsh = g;
  }
  __syncthreads();
  int g = gsh;
  const float* W = w1 + (size_t)(g * E_ + e) * D_ * FF_;
  const float* bias = b1 + (size_t)(g * E_ + e) * FF_;
  float acc[4][4] = {};
  for (int k0 = 0; k0 < D_; k0 += 16) {
#pragma unroll
    for (int i = 0; i < 4; ++i) {
      int ee = i * 256 + tid;
      int r = ee >> 4, c = ee & 15;
      int tok = toks[r];
      As[c][r] = (tok >= 0) ? X[(size_t)tok * D_ + k0 + c] : 0.f;
    }
#pragma unroll
    for (int i = 0; i < 4; ++i) {
      int ee = i * 256 + tid;
      int r = ee >> 6, c = ee & 63;
      Bs[r][c] = W[(size_t)(k0 + r) * FF_ + tn * 64 + c];
    }
    __syncthreads();
    mm_tile(As, Bs, ty, tx, acc);
    __syncthreads();
  }
#pragma unroll
  for (int i = 0; i < 4; ++i) {
    int slot = slot0 + ty * 4 + i;
#pragma unroll
    for (int j = 0; j < 4; ++j) {
      int f = tn * 64 + tx * 4 + j;
      hid[(size_t)slot * FF_ + f] = gelu_f(acc[i][j] + bias[f]);
    }
  }
}

// ------- MoE FF2: d_out[tok,d] += 0.5*(hid[slot]*w2[g,e] + b2[g,e,d]) --------
__global__ __launch_bounds__(256) void ff2_kernel(
    const float* __restrict__ hid, const float* __restrict__ w2,
    const float* __restrict__ b2, const int* __restrict__ list,
    const int* __restrict__ poff, int e, float* __restrict__ out) {
  __shared__ __align__(16) float As[16][68];
  __shared__ __align__(16) float Bs[16][68];
  __shared__ int toks[64];
  __shared__ int gsh;
  int tm = blockIdx.x, tn = blockIdx.y;
  int slot0 = tm * 64;
  if (slot0 >= poff[G_]) return;
  int tid = threadIdx.x, tx = tid & 15, ty = tid >> 4;
  if (tid < 64) toks[tid] = list[slot0 + tid];
  if (tid == 0) {
    int g = 0;
    while (slot0 >= poff[g + 1]) ++g;
    gsh = g;
  }
  __syncthreads();
  int g = gsh;
  const float* W = w2 + (size_t)(g * E_ + e) * FF_ * D_;
  const float* bias = b2 + (size_t)(g * E_ + e) * D_;
  float acc[4][4] = {};
  for (int k0 = 0; k0 < FF_; k0 += 16) {
#pragma unroll
    for (int i = 0; i < 4; ++i) {
      int ee = i * 256 + tid;
      int r = ee >> 4, c = ee & 15;
      As[c][r] = hid[(size_t)(slot0 + r) * FF_ + k0 + c];
    }
#pragma unroll
    for (int i = 0; i < 4; ++i) {
      int ee = i * 256 + tid;
      int r = ee >> 6, c = ee & 63;
      Bs[r][c] = W[(size_t)(k0 + r) * D_ + tn * 64 + c];
    }
    __syncthreads();
    mm_tile(As, Bs, ty, tx, acc);
    __syncthreads();
  }
#pragma unroll
  for (int i = 0; i < 4; ++i) {
    int tok = toks[ty * 4 + i];
    if (tok < 0) continue;
#pragma unroll
    for (int j = 0; j < 4; ++j) {
      int d = tn * 64 + tx * 4 + j;
      out[(size_t)tok * D_ + d] += 0.5f * (acc[i][j] + bias[d]);
    }
  }
}

}  // namespace

extern "C" void kernel_launch(void* const* d_in, const int* in_sizes, int n_in,
                              void* d_out, int out_size, void* d_ws, size_t ws_size,
                              hipStream_t stream) {
  const float* x = (const float*)d_in[0];
  const int* gid = (const int*)d_in[1];
  const float* ln1s = (const float*)d_in[2];
  const float* ln1b = (const float*)d_in[3];
  const float* ck = (const float*)d_in[4];
  const float* cb = (const float*)d_in[5];
  const float* ln2s = (const float*)d_in[6];
  const float* ln2b = (const float*)d_in[7];
  const float* wq = (const float*)d_in[8];
  const float* bq = (const float*)d_in[9];
  const float* wk = (const float*)d_in[10];
  const float* bk = (const float*)d_in[11];
  const float* wv = (const float*)d_in[12];
  const float* bv = (const float*)d_in[13];
  const float* wo = (const float*)d_in[14];
  const float* bo = (const float*)d_in[15];
  const float* w1 = (const float*)d_in[16];
  const float* b1 = (const float*)d_in[17];
  const float* w2 = (const float*)d_in[18];
  const float* b2 = (const float*)d_in[19];
  float* out = (float*)d_out;

  char* ws = (char*)d_ws;
  float* bufA = (float*)(ws);                        // 8MB: h1 / h2 / o
  float* bufB = (float*)(ws + (8u << 20));           // 8MB: x1 / x2
  float* bufQ = (float*)(ws + (16u << 20));          // 8MB
  float* bufK = (float*)(ws + (24u << 20));          // 8MB
  float* bufV = (float*)(ws + (32u << 20));          // 8MB
  float* hid = (float*)(ws + (40u << 20));           // 4352*2048*4 = 35651584
  int* list = (int*)(ws + (40u << 20) + (size_t)PADCAP_ * FF_ * 4);
  int* poff = list + PADCAP_;

  bucket_kernel<<<1, 1024, 0, stream>>>(gid, list, poff);
  ln_kernel<<<N_, 256, 0, stream>>>(x, bufA, ln1s, ln1b);
  conv_kernel<<<dim3(N_ / 64, D_ / 64), 256, 0, stream>>>(bufA, ck, cb, x, bufB);
  ln_kernel<<<N_, 256, 0, stream>>>(bufB, bufA, ln2s, ln2b);
  gemm_bias_kernel<<<dim3(N_ / 64, D_ / 64), 256, 0, stream>>>(bufA, wq, bq, bufQ, N_, D_, D_);
  gemm_bias_kernel<<<dim3(N_ / 64, D_ / 64), 256, 0, stream>>>(bufA, wk, bk, bufK, N_, D_, D_);
  gemm_bias_kernel<<<dim3(N_ / 64, D_ / 64), 256, 0, stream>>>(bufA, wv, bv, bufV, N_, D_, D_);
  attn_kernel<<<dim3(S_ / 32, H_, B_), 256, 0, stream>>>(bufQ, bufK, bufV, bufA);
  gemm_wo_kernel<<<dim3(N_ / 64, D_ / 64), 256, 0, stream>>>(bufA, wo, bo, bufB, out, bufB);
  for (int e = 0; e < E_; ++e) {
    ff1_kernel<<<dim3(68, FF_ / 64), 256, 0, stream>>>(bufB, w1, b1, list, poff, e, hid);
    ff2_kernel<<<dim3(68, D_ / 64), 256, 0, stream>>>(hid, w2, b2, list, poff, e, out);
  }
}

// Round 2
// 1176.544 us; speedup vs baseline: 2.4872x; 2.4872x over previous
//
#include <hip/hip_runtime.h>
#include <hip/hip_bf16.h>
#include <math.h>
#include <stdint.h>

namespace {

constexpr int B_ = 2, S_ = 2048, D_ = 512, H_ = 8, HD_ = 64, K_ = 31,
              FF_ = 2048, G_ = 4, E_ = 2;
constexpr int N_ = B_ * S_;
constexpr int SP_ = S_ + 30;   // padded rows per batch (15 zeros each side)
constexpr float EPS_ = 1e-6f;
constexpr int PADCAP_ = 4608;  // 4096 + 4*127 rounded up to 128-tiles

typedef __bf16 bf16x8 __attribute__((ext_vector_type(8)));
typedef float f32x4 __attribute__((ext_vector_type(4)));

__device__ __forceinline__ uint16_t f2bf(float f) {
  union { float f; uint32_t u; } v; v.f = f;
  uint32_t r = v.u + 0x7FFFu + ((v.u >> 16) & 1u);
  return (uint16_t)(r >> 16);
}

__device__ __forceinline__ float gelu_f(float x) {
  const float c = 0.7978845608028654f;  // sqrt(2/pi)
  return 0.5f * x * (1.0f + tanhf(c * (x + 0.044715f * x * x * x)));
}

#define GLOAD_LDS16(gsrc, ldst)                                              \
  __builtin_amdgcn_global_load_lds(                                          \
      (const __attribute__((address_space(1))) void*)(gsrc),                 \
      (__attribute__((address_space(3))) void*)(ldst), 16, 0, 0)

#define SYNC_STAGE()                                   \
  do {                                                 \
    asm volatile("s_waitcnt vmcnt(0)" ::: "memory");   \
    __syncthreads();                                   \
  } while (0)

// Stage A[128][32] and B^T[128][32] bf16 tiles into LDS via global_load_lds.
// Thread t covers 16B chunks e0=t, e1=256+t: row=e>>2, col=(e&3)*8.
__device__ __forceinline__ void stage_pair(const uint16_t* Ak, int lda,
                                           const uint16_t* Bk, int ldb,
                                           int t, uint16_t* As, uint16_t* Bs) {
  int row = t >> 2, col = (t & 3) * 8, uoff = (t & ~63) * 8;
  GLOAD_LDS16(Ak + (size_t)row * lda + col, As + uoff);
  GLOAD_LDS16(Bk + (size_t)row * ldb + col, Bs + uoff);
  GLOAD_LDS16(Ak + (size_t)(row + 64) * lda + col, As + 2048 + uoff);
  GLOAD_LDS16(Bk + (size_t)(row + 64) * ldb + col, Bs + 2048 + uoff);
}

// One K=32 step: wave (wr,wc) computes 64x64 via 4x4 frags of 16x16x32.
// A-frag: lane holds A[row=l&15][k=(l>>4)*8+j]; B-frag from B^T rows (cols of B).
__device__ __forceinline__ void kstep_compute(const uint16_t* As, const uint16_t* Bs,
                                              int wr, int wc, int l15, int k8,
                                              f32x4 acc[4][4]) {
  bf16x8 a[4], b[4];
#pragma unroll
  for (int m = 0; m < 4; ++m)
    a[m] = *(const bf16x8*)(As + (size_t)(wr * 64 + m * 16 + l15) * 32 + k8);
#pragma unroll
  for (int n = 0; n < 4; ++n)
    b[n] = *(const bf16x8*)(Bs + (size_t)(wc * 64 + n * 16 + l15) * 32 + k8);
#pragma unroll
  for (int m = 0; m < 4; ++m)
#pragma unroll
    for (int n = 0; n < 4; ++n)
      acc[m][n] = __builtin_amdgcn_mfma_f32_16x16x32_bf16(a[m], b[n], acc[m][n], 0, 0, 0);
}

// ---------------- f32 [R][C] -> bf16 transposed [C][R], batched -------------
__global__ __launch_bounds__(256) void transpose_bf16_kernel(
    const float* __restrict__ src, uint16_t* __restrict__ dst, int R, int C) {
  __shared__ float tile[32][33];
  size_t bs = (size_t)R * C;
  const float* s = src + blockIdx.z * bs;
  uint16_t* d = dst + blockIdx.z * bs;
  int c0 = blockIdx.x * 32, r0 = blockIdx.y * 32;
  int t = threadIdx.x, tc = t & 31, tr = t >> 5;
#pragma unroll
  for (int i = 0; i < 4; ++i) {
    int r = tr + i * 8;
    tile[r][tc] = s[(size_t)(r0 + r) * C + c0 + tc];
  }
  __syncthreads();
#pragma unroll
  for (int i = 0; i < 4; ++i) {
    int rr = tr + i * 8;
    d[(size_t)(c0 + rr) * R + r0 + tc] = f2bf(tile[tc][rr]);
  }
}

// ---------------- zero pad rows of Hpad + zero row N_ of x2bf ---------------
__global__ __launch_bounds__(256) void zero_pad_kernel(uint16_t* Hpad, uint16_t* x2bf) {
  int ib = blockIdx.x, t = threadIdx.x;
  uint16_t* dst;
  if (ib < 60) {
    int b = ib / 30, j = ib % 30;
    int row = b * SP_ + (j < 15 ? j : 2048 + j);  // first 15 / last 15 rows
    dst = Hpad + (size_t)row * D_;
  } else {
    dst = x2bf + (size_t)N_ * D_;
  }
  dst[t] = 0;
  dst[t + 256] = 0;
}

// ---------------- LayerNorm -> bf16 (optionally into padded Hpad) -----------
__global__ __launch_bounds__(256) void ln_bf16_kernel(
    const float* __restrict__ in, uint16_t* __restrict__ out,
    const float* __restrict__ scale, const float* __restrict__ bias, int hpad) {
  int row = blockIdx.x;
  const float* xr = in + (size_t)row * D_;
  int t = threadIdx.x;
  float v0 = xr[t], v1 = xr[t + 256];
  float s = v0 + v1, sq = v0 * v0 + v1 * v1;
  for (int o = 32; o > 0; o >>= 1) {
    s += __shfl_down(s, o);
    sq += __shfl_down(sq, o);
  }
  __shared__ float sm[8];
  __shared__ float mr[2];
  int lane = t & 63, wid = t >> 6;
  if (lane == 0) { sm[wid] = s; sm[wid + 4] = sq; }
  __syncthreads();
  if (t == 0) {
    float ts = sm[0] + sm[1] + sm[2] + sm[3];
    float tq = sm[4] + sm[5] + sm[6] + sm[7];
    float m = ts / D_;
    mr[0] = m;
    mr[1] = rsqrtf(tq / D_ - m * m + EPS_);
  }
  __syncthreads();
  float m = mr[0], rs = mr[1];
  size_t drow = hpad ? ((size_t)(row >> 11) * SP_ + 15 + (row & 2047)) : (size_t)row;
  uint16_t* orow = out + drow * D_;
  orow[t] = f2bf((v0 - m) * rs * scale[t] + bias[t]);
  orow[t + 256] = f2bf((v1 - m) * rs * scale[t + 256] + bias[t + 256]);
}

// ---------------- conv as 31 shifted GEMMs, split-K over taps (4 slices) ----
__global__ __launch_bounds__(256) void conv_mfma_kernel(
    const uint16_t* __restrict__ Hpad, const uint16_t* __restrict__ ckT,
    float* __restrict__ Pout) {
  __shared__ __align__(16) uint16_t As[4096], Bs[4096];
  int tm = blockIdx.x, tn = blockIdx.y, ks = blockIdx.z;
  int t = threadIdx.x;
  int w = t >> 6, l = t & 63, l15 = l & 15, k8 = (l >> 4) * 8;
  int wr = w >> 1, wc = w & 1;
  int row0 = tm * 128, b = row0 >> 11, s0 = row0 & 2047;
  f32x4 acc[4][4] = {};
  int kb = ks * 8, ke = (ks == 3) ? 31 : kb + 8;
  for (int k = kb; k < ke; ++k) {
    const uint16_t* Ak = Hpad + (size_t)(b * SP_ + s0 + k) * D_;
    const uint16_t* Bk = ckT + (size_t)k * D_ * D_ + (size_t)(tn * 128) * D_;
    for (int d0 = 0; d0 < D_; d0 += 32) {
      stage_pair(Ak + d0, D_, Bk + d0, D_, t, As, Bs);
      SYNC_STAGE();
      kstep_compute(As, Bs, wr, wc, l15, k8, acc);
      __syncthreads();
    }
  }
  float* P = Pout + (size_t)ks * N_ * D_;
#pragma unroll
  for (int m = 0; m < 4; ++m) {
    int r = row0 + wr * 64 + m * 16 + (l >> 4) * 4;
#pragma unroll
    for (int n = 0; n < 4; ++n) {
      int c = tn * 128 + wc * 64 + n * 16 + l15;
#pragma unroll
      for (int j = 0; j < 4; ++j)
        P[(size_t)(r + j) * D_ + c] = acc[m][n][j];
    }
  }
}

// ---------------- conv epilogue: x1 = gelu(P0+P1+P2+P3 + cb) + x ------------
__global__ __launch_bounds__(256) void conv_epi_kernel(
    const float* __restrict__ P, const float* __restrict__ cb,
    const float* __restrict__ xres, float* __restrict__ x1) {
  int idx = blockIdx.x * 256 + threadIdx.x;  // float4 index
  const float4* p0 = (const float4*)P;
  const float4* p1 = (const float4*)(P + (size_t)N_ * D_);
  const float4* p2 = (const float4*)(P + (size_t)2 * N_ * D_);
  const float4* p3 = (const float4*)(P + (size_t)3 * N_ * D_);
  float4 a = p0[idx], b = p1[idx], c = p2[idx], d = p3[idx];
  float4 bias = *(const float4*)(cb + ((idx * 4) & (D_ - 1)));
  float4 r = ((const float4*)xres)[idx];
  float4 o;
  o.x = gelu_f(a.x + b.x + c.x + d.x + bias.x) + r.x;
  o.y = gelu_f(a.y + b.y + c.y + d.y + bias.y) + r.y;
  o.z = gelu_f(a.z + b.z + c.z + d.z + bias.z) + r.z;
  o.w = gelu_f(a.w + b.w + c.w + d.w + bias.w) + r.w;
  ((float4*)x1)[idx] = o;
}

// ---------------- fused QKV GEMM: [4096,512] x [512,1536] -------------------
__global__ __launch_bounds__(256) void gemm_qkv_kernel(
    const uint16_t* __restrict__ A, const uint16_t* __restrict__ BT,
    const float* __restrict__ bq, const float* __restrict__ bk,
    const float* __restrict__ bv, float* __restrict__ Qb,
    float* __restrict__ Kb, float* __restrict__ Vb) {
  __shared__ __align__(16) uint16_t As[4096], Bs[4096];
  int tm = blockIdx.x, tn = blockIdx.y;
  int t = threadIdx.x;
  int w = t >> 6, l = t & 63, l15 = l & 15, k8 = (l >> 4) * 8;
  int wr = w >> 1, wc = w & 1;
  int row0 = tm * 128;
  f32x4 acc[4][4] = {};
  const uint16_t* Ab = A + (size_t)row0 * D_;
  const uint16_t* Bb = BT + (size_t)(tn * 128) * D_;
  for (int k0 = 0; k0 < D_; k0 += 32) {
    stage_pair(Ab + k0, D_, Bb + k0, D_, t, As, Bs);
    SYNC_STAGE();
    kstep_compute(As, Bs, wr, wc, l15, k8, acc);
    __syncthreads();
  }
  int sel = tn >> 2, col0 = (tn & 3) * 128;
  float* dst = sel == 0 ? Qb : (sel == 1 ? Kb : Vb);
  const float* bias = sel == 0 ? bq : (sel == 1 ? bk : bv);
#pragma unroll
  for (int m = 0; m < 4; ++m) {
    int r = row0 + wr * 64 + m * 16 + (l >> 4) * 4;
#pragma unroll
    for (int n = 0; n < 4; ++n) {
      int c = col0 + wc * 64 + n * 16 + l15;
#pragma unroll
      for (int j = 0; j < 4; ++j)
        dst[(size_t)(r + j) * D_ + c] = acc[m][n][j] + bias[c];
    }
  }
}

// ---------------- WO GEMM + bias + residual -> out (f32) + x2 (bf16) --------
__global__ __launch_bounds__(256) void gemm_wo_kernel(
    const uint16_t* __restrict__ A, const uint16_t* __restrict__ BT,
    const float* __restrict__ bo, const float* __restrict__ res,
    float* __restrict__ out, uint16_t* __restrict__ x2bf) {
  __shared__ __align__(16) uint16_t As[4096], Bs[4096];
  int tm = blockIdx.x, tn = blockIdx.y;
  int t = threadIdx.x;
  int w = t >> 6, l = t & 63, l15 = l & 15, k8 = (l >> 4) * 8;
  int wr = w >> 1, wc = w & 1;
  int row0 = tm * 128;
  f32x4 acc[4][4] = {};
  const uint16_t* Ab = A + (size_t)row0 * D_;
  const uint16_t* Bb = BT + (size_t)(tn * 128) * D_;
  for (int k0 = 0; k0 < D_; k0 += 32) {
    stage_pair(Ab + k0, D_, Bb + k0, D_, t, As, Bs);
    SYNC_STAGE();
    kstep_compute(As, Bs, wr, wc, l15, k8, acc);
    __syncthreads();
  }
#pragma unroll
  for (int m = 0; m < 4; ++m) {
    int r = row0 + wr * 64 + m * 16 + (l >> 4) * 4;
#pragma unroll
    for (int n = 0; n < 4; ++n) {
      int c = tn * 128 + wc * 64 + n * 16 + l15;
#pragma unroll
      for (int j = 0; j < 4; ++j) {
        float v = acc[m][n][j] + bo[c] + res[(size_t)(r + j) * D_ + c];
        out[(size_t)(r + j) * D_ + c] = v;
        x2bf[(size_t)(r + j) * D_ + c] = f2bf(v);
      }
    }
  }
}

// ---------------- flash attention (fp32 VALU), bf16 output ------------------
__global__ __launch_bounds__(256) void attn_kernel(
    const float* __restrict__ q, const float* __restrict__ k,
    const float* __restrict__ v, uint16_t* __restrict__ o) {
  constexpr int QT = 32, KT = 64;
  __shared__ float Qs[QT][HD_];
  __shared__ float Ks[KT][HD_ + 1];
  __shared__ float Vs[KT][HD_ + 1];
  __shared__ float Ps[QT][KT + 1];
  __shared__ float Ms[QT], Ls[QT];
  int qt = blockIdx.x, h = blockIdx.y, b = blockIdx.z;
  int tid = threadIdx.x;
  int r = tid >> 3, gsub = tid & 7;
  const float scale = 0.125f;
#pragma unroll
  for (int i = 0; i < 8; ++i) {
    int e = i * 256 + tid;
    int rr = e >> 6, d = e & 63;
    Qs[rr][d] = q[(size_t)(b * S_ + qt * QT + rr) * D_ + h * HD_ + d] * scale;
  }
  float oreg[8] = {};
  if (tid < QT) { Ms[tid] = -INFINITY; Ls[tid] = 0.f; }
  __syncthreads();
  for (int kt = 0; kt < S_ / KT; ++kt) {
#pragma unroll
    for (int i = 0; i < 16; ++i) {
      int e = i * 256 + tid;
      int j = e >> 6, d = e & 63;
      size_t src = (size_t)(b * S_ + kt * KT + j) * D_ + h * HD_ + d;
      Ks[j][d] = k[src];
      Vs[j][d] = v[src];
    }
    __syncthreads();
    float sc[8];
#pragma unroll
    for (int jj = 0; jj < 8; ++jj) {
      int j = gsub * 8 + jj;
      float acc = 0.f;
#pragma unroll
      for (int d = 0; d < HD_; ++d) acc += Qs[r][d] * Ks[j][d];
      sc[jj] = acc;
    }
    float mx = sc[0];
#pragma unroll
    for (int jj = 1; jj < 8; ++jj) mx = fmaxf(mx, sc[jj]);
    for (int o_ = 1; o_ < 8; o_ <<= 1) mx = fmaxf(mx, __shfl_xor(mx, o_));
    float mold = Ms[r];
    float mnew = fmaxf(mold, mx);
    float sum = 0.f;
#pragma unroll
    for (int jj = 0; jj < 8; ++jj) {
      float p = __expf(sc[jj] - mnew);
      Ps[r][gsub * 8 + jj] = p;
      sum += p;
    }
    for (int o_ = 1; o_ < 8; o_ <<= 1) sum += __shfl_xor(sum, o_);
    float corr = __expf(mold - mnew);
    if (gsub == 0) {
      Ms[r] = mnew;
      Ls[r] = Ls[r] * corr + sum;
    }
#pragma unroll
    for (int dd = 0; dd < 8; ++dd) oreg[dd] *= corr;
    for (int j = 0; j < KT; ++j) {
      float p = Ps[r][j];
#pragma unroll
      for (int dd = 0; dd < 8; ++dd) oreg[dd] += p * Vs[j][gsub * 8 + dd];
    }
    __syncthreads();
  }
  float inv = 1.f / Ls[r];
#pragma unroll
  for (int dd = 0; dd < 8; ++dd)
    o[(size_t)(b * S_ + qt * QT + r) * D_ + h * HD_ + gsub * 8 + dd] =
        f2bf(oreg[dd] * inv);
}

// ---------------- MoE bucketing: group tokens, pad to 128 -------------------
__global__ __launch_bounds__(1024) void bucket_kernel(
    const int* __restrict__ gid, int* __restrict__ list, int* __restrict__ poff) {
  __shared__ int cnt[G_], cur[G_];
  int t = threadIdx.x;
  if (t < G_) cnt[t] = 0;
  __syncthreads();
  for (int i = t; i < N_; i += 1024) atomicAdd(&cnt[gid[i]], 1);
  __syncthreads();
  if (t == 0) {
    int off = 0;
    for (int g = 0; g < G_; ++g) {
      poff[g] = off;
      cur[g] = off;
      off += (cnt[g] + 127) & ~127;
    }
    poff[G_] = off;
  }
  __syncthreads();
  for (int i = t; i < PADCAP_; i += 1024) list[i] = N_;  // pad -> zero row
  __syncthreads();
  for (int i = t; i < N_; i += 1024) {
    int p = atomicAdd(&cur[gid[i]], 1);
    list[p] = i;
  }
}

// ---------------- MoE FF1 (gathered A), both experts via grid.z -------------
__global__ __launch_bounds__(256) void ff1_mfma_kernel(
    const uint16_t* __restrict__ X, const uint16_t* __restrict__ w1T,
    const float* __restrict__ b1, const int* __restrict__ list,
    const int* __restrict__ poff, uint16_t* __restrict__ hid) {
  __shared__ __align__(16) uint16_t As[4096], Bs[4096];
  int tm = blockIdx.x, tn = blockIdx.y, e = blockIdx.z;
  int slot0 = tm * 128;
  if (slot0 >= poff[G_]) return;
  int g = 0;
#pragma unroll
  for (int gg = 1; gg < G_; ++gg) g += (slot0 >= poff[gg]);
  int t = threadIdx.x;
  int w = t >> 6, l = t & 63, l15 = l & 15, k8 = (l >> 4) * 8;
  int wr = w >> 1, wc = w & 1;
  int tokA = list[slot0 + (t >> 2)];
  int tokB = list[slot0 + 64 + (t >> 2)];
  int col = (t & 3) * 8, uoff = (t & ~63) * 8;
  f32x4 acc[4][4] = {};
  const uint16_t* Bb = w1T + ((size_t)(g * E_ + e) * FF_ + tn * 128) * D_;
  for (int k0 = 0; k0 < D_; k0 += 32) {
    GLOAD_LDS16(X + (size_t)tokA * D_ + k0 + col, As + uoff);
    GLOAD_LDS16(X + (size_t)tokB * D_ + k0 + col, As + 2048 + uoff);
    int row = t >> 2;
    GLOAD_LDS16(Bb + (size_t)row * D_ + k0 + col, Bs + uoff);
    GLOAD_LDS16(Bb + (size_t)(row + 64) * D_ + k0 + col, Bs + 2048 + uoff);
    SYNC_STAGE();
    kstep_compute(As, Bs, wr, wc, l15, k8, acc);
    __syncthreads();
  }
  const float* bias = b1 + (size_t)(g * E_ + e) * FF_;
  uint16_t* hidE = hid + (size_t)e * PADCAP_ * FF_;
#pragma unroll
  for (int m = 0; m < 4; ++m) {
    int r = slot0 + wr * 64 + m * 16 + (l >> 4) * 4;
#pragma unroll
    for (int n = 0; n < 4; ++n) {
      int c = tn * 128 + wc * 64 + n * 16 + l15;
#pragma unroll
      for (int j = 0; j < 4; ++j)
        hidE[(size_t)(r + j) * FF_ + c] = f2bf(gelu_f(acc[m][n][j] + bias[c]));
    }
  }
}

// ---------------- MoE FF2: both experts accumulated, scatter-add to out -----
__global__ __launch_bounds__(256) void ff2_mfma_kernel(
    const uint16_t* __restrict__ hid, const uint16_t* __restrict__ w2T,
    const float* __restrict__ b2, const int* __restrict__ list,
    const int* __restrict__ poff, float* __restrict__ out) {
  __shared__ __align__(16) uint16_t As[4096], Bs[4096];
  int tm = blockIdx.x, tn = blockIdx.y;
  int slot0 = tm * 128;
  if (slot0 >= poff[G_]) return;
  int g = 0;
#pragma unroll
  for (int gg = 1; gg < G_; ++gg) g += (slot0 >= poff[gg]);
  int t = threadIdx.x;
  int w = t >> 6, l = t & 63, l15 = l & 15, k8 = (l >> 4) * 8;
  int wr = w >> 1, wc = w & 1;
  f32x4 acc[4][4] = {};
  for (int e = 0; e < E_; ++e) {
    const uint16_t* Ab = hid + (size_t)e * PADCAP_ * FF_ + (size_t)slot0 * FF_;
    const uint16_t* Bb = w2T + (size_t)(g * E_ + e) * D_ * FF_ + (size_t)(tn * 128) * FF_;
    for (int k0 = 0; k0 < FF_; k0 += 32) {
      stage_pair(Ab + k0, FF_, Bb + k0, FF_, t, As, Bs);
      SYNC_STAGE();
      kstep_compute(As, Bs, wr, wc, l15, k8, acc);
      __syncthreads();
    }
  }
  const float* b2a = b2 + (size_t)(g * E_) * D_;
  const float* b2b = b2 + (size_t)(g * E_ + 1) * D_;
#pragma unroll
  for (int m = 0; m < 4; ++m) {
    int rbase = slot0 + wr * 64 + m * 16 + (l >> 4) * 4;
#pragma unroll
    for (int j = 0; j < 4; ++j) {
      int tok = list[rbase + j];
      if (tok >= N_) continue;
#pragma unroll
      for (int n = 0; n < 4; ++n) {
        int c = tn * 128 + wc * 64 + n * 16 + l15;
        out[(size_t)tok * D_ + c] += 0.5f * (acc[m][n][j] + b2a[c] + b2b[c]);
      }
    }
  }
}

}  // namespace

extern "C" void kernel_launch(void* const* d_in, const int* in_sizes, int n_in,
                              void* d_out, int out_size, void* d_ws, size_t ws_size,
                              hipStream_t stream) {
  const float* x = (const float*)d_in[0];
  const int* gid = (const int*)d_in[1];
  const float* ln1s = (const float*)d_in[2];
  const float* ln1b = (const float*)d_in[3];
  const float* ck = (const float*)d_in[4];
  const float* cb = (const float*)d_in[5];
  const float* ln2s = (const float*)d_in[6];
  const float* ln2b = (const float*)d_in[7];
  const float* wq = (const float*)d_in[8];
  const float* bq = (const float*)d_in[9];
  const float* wk = (const float*)d_in[10];
  const float* bk = (const float*)d_in[11];
  const float* wv = (const float*)d_in[12];
  const float* bv = (const float*)d_in[13];
  const float* wo = (const float*)d_in[14];
  const float* bo = (const float*)d_in[15];
  const float* w1 = (const float*)d_in[16];
  const float* b1 = (const float*)d_in[17];
  const float* w2 = (const float*)d_in[18];
  const float* b2 = (const float*)d_in[19];
  float* out = (float*)d_out;

  char* ws = (char*)d_ws;
  // Region A (38 MiB), time-multiplexed:
  //  phase1: P[4] f32 partials (4 x 8 MiB)
  //  phase2: ln2bf(4 MiB) | Q(8) | K(8) | V(8) | obf(4)
  //  phase3: hidbf (2*4608*2048*2 = 36 MiB)
  char* A = ws;
  float* P = (float*)A;
  uint16_t* ln2bf = (uint16_t*)A;
  float* Qb = (float*)(A + (4ull << 20));
  float* Kb = (float*)(A + (12ull << 20));
  float* Vb = (float*)(A + (20ull << 20));
  uint16_t* obf = (uint16_t*)(A + (28ull << 20));
  uint16_t* hidbf = (uint16_t*)A;

  float* x1 = (float*)(ws + (38ull << 20));
  uint16_t* Hpad = (uint16_t*)(ws + (46ull << 20));   // 2*2078*512 bf16
  uint16_t* ckT = (uint16_t*)(ws + (51ull << 20));    // [31][512][512]
  uint16_t* wqkvT = (uint16_t*)(ws + (67ull << 20));  // [1536][512]
  uint16_t* woT = (uint16_t*)(ws + (69ull << 20));    // [512][512]
  uint16_t* w1T = (uint16_t*)(ws + (70ull << 20));    // [8][2048][512]
  uint16_t* w2T = (uint16_t*)(ws + (86ull << 20));    // [8][512][2048]
  uint16_t* x2bf = (uint16_t*)(ws + (102ull << 20));  // [4097][512]
  int* list = (int*)(ws + (107ull << 20));
  int* poff = list + PADCAP_;

  // weight conversion / transposition (bf16, B^T layout)
  transpose_bf16_kernel<<<dim3(16, 16, 31), 256, 0, stream>>>(ck, ckT, 512, 512);
  transpose_bf16_kernel<<<dim3(16, 16, 1), 256, 0, stream>>>(wq, wqkvT, 512, 512);
  transpose_bf16_kernel<<<dim3(16, 16, 1), 256, 0, stream>>>(wk, wqkvT + 512 * 512, 512, 512);
  transpose_bf16_kernel<<<dim3(16, 16, 1), 256, 0, stream>>>(wv, wqkvT + 2 * 512 * 512, 512, 512);
  transpose_bf16_kernel<<<dim3(16, 16, 1), 256, 0, stream>>>(wo, woT, 512, 512);
  transpose_bf16_kernel<<<dim3(64, 16, 8), 256, 0, stream>>>(w1, w1T, 512, 2048);
  transpose_bf16_kernel<<<dim3(16, 64, 8), 256, 0, stream>>>(w2, w2T, 2048, 512);
  zero_pad_kernel<<<61, 256, 0, stream>>>(Hpad, x2bf);
  bucket_kernel<<<1, 1024, 0, stream>>>(gid, list, poff);

  // conv sublayer
  ln_bf16_kernel<<<N_, 256, 0, stream>>>(x, Hpad, ln1s, ln1b, 1);
  conv_mfma_kernel<<<dim3(32, 4, 4), 256, 0, stream>>>(Hpad, ckT, P);
  conv_epi_kernel<<<2048, 256, 0, stream>>>(P, cb, x, x1);

  // attention sublayer
  ln_bf16_kernel<<<N_, 256, 0, stream>>>(x1, ln2bf, ln2s, ln2b, 0);
  gemm_qkv_kernel<<<dim3(32, 12), 256, 0, stream>>>(ln2bf, wqkvT, bq, bk, bv, Qb, Kb, Vb);
  attn_kernel<<<dim3(S_ / 32, H_, B_), 256, 0, stream>>>(Qb, Kb, Vb, obf);
  gemm_wo_kernel<<<dim3(32, 4), 256, 0, stream>>>(obf, woT, bo, x1, out, x2bf);

  // MoE sublayer
  ff1_mfma_kernel<<<dim3(36, 16, 2), 256, 0, stream>>>(x2bf, w1T, b1, list, poff, hidbf);
  ff2_mfma_kernel<<<dim3(36, 4), 256, 0, stream>>>(hidbf, w2T, b2, list, poff, out);
}

// Round 3
// 389.592 us; speedup vs baseline: 7.5111x; 3.0199x over previous
//
#include <hip/hip_runtime.h>
#include <hip/hip_bf16.h>
#include <math.h>
#include <stdint.h>

namespace {

constexpr int B_ = 2, S_ = 2048, D_ = 512, H_ = 8, HD_ = 64, K_ = 31,
              FF_ = 2048, G_ = 4, E_ = 2;
constexpr int N_ = B_ * S_;
constexpr int SP_ = S_ + 30;   // padded rows per batch (15 zeros each side)
constexpr float EPS_ = 1e-6f;
constexpr int PADCAP_ = 4608;  // 4096 + 4*127 rounded up to 128-tiles

typedef __bf16 bf16x8 __attribute__((ext_vector_type(8)));
typedef unsigned short u16x8 __attribute__((ext_vector_type(8)));
typedef float f32x4 __attribute__((ext_vector_type(4)));

__device__ __forceinline__ uint16_t f2bf(float f) {
  union { float f; uint32_t u; } v; v.f = f;
  uint32_t r = v.u + 0x7FFFu + ((v.u >> 16) & 1u);
  return (uint16_t)(r >> 16);
}

__device__ __forceinline__ float gelu_f(float x) {
  const float c = 0.7978845608028654f;  // sqrt(2/pi)
  return 0.5f * x * (1.0f + tanhf(c * (x + 0.044715f * x * x * x)));
}

#define GLOAD_LDS16(gsrc, ldst)                                              \
  __builtin_amdgcn_global_load_lds(                                          \
      (const __attribute__((address_space(1))) void*)(gsrc),                 \
      (__attribute__((address_space(3))) void*)(ldst), 16, 0, 0)

#define SYNC_STAGE()                                   \
  do {                                                 \
    asm volatile("s_waitcnt vmcnt(0)" ::: "memory");   \
    __syncthreads();                                   \
  } while (0)

// Stage A[128][32] and B^T[128][32] bf16 tiles into LDS via global_load_lds.
__device__ __forceinline__ void stage_pair(const uint16_t* Ak, int lda,
                                           const uint16_t* Bk, int ldb,
                                           int t, uint16_t* As, uint16_t* Bs) {
  int row = t >> 2, col = (t & 3) * 8, uoff = (t & ~63) * 8;
  GLOAD_LDS16(Ak + (size_t)row * lda + col, As + uoff);
  GLOAD_LDS16(Bk + (size_t)row * ldb + col, Bs + uoff);
  GLOAD_LDS16(Ak + (size_t)(row + 64) * lda + col, As + 2048 + uoff);
  GLOAD_LDS16(Bk + (size_t)(row + 64) * ldb + col, Bs + 2048 + uoff);
}

__device__ __forceinline__ void kstep_compute(const uint16_t* As, const uint16_t* Bs,
                                              int wr, int wc, int l15, int k8,
                                              f32x4 acc[4][4]) {
  bf16x8 a[4], b[4];
#pragma unroll
  for (int m = 0; m < 4; ++m)
    a[m] = *(const bf16x8*)(As + (size_t)(wr * 64 + m * 16 + l15) * 32 + k8);
#pragma unroll
  for (int n = 0; n < 4; ++n)
    b[n] = *(const bf16x8*)(Bs + (size_t)(wc * 64 + n * 16 + l15) * 32 + k8);
#pragma unroll
  for (int m = 0; m < 4; ++m)
#pragma unroll
    for (int n = 0; n < 4; ++n)
      acc[m][n] = __builtin_amdgcn_mfma_f32_16x16x32_bf16(a[m], b[n], acc[m][n], 0, 0, 0);
}

// ---------------- f32 [R][C] -> bf16 transposed [C][R], batched -------------
__global__ __launch_bounds__(256) void transpose_bf16_kernel(
    const float* __restrict__ src, uint16_t* __restrict__ dst, int R, int C) {
  __shared__ float tile[32][33];
  size_t bs = (size_t)R * C;
  const float* s = src + blockIdx.z * bs;
  uint16_t* d = dst + blockIdx.z * bs;
  int c0 = blockIdx.x * 32, r0 = blockIdx.y * 32;
  int t = threadIdx.x, tc = t & 31, tr = t >> 5;
#pragma unroll
  for (int i = 0; i < 4; ++i) {
    int r = tr + i * 8;
    tile[r][tc] = s[(size_t)(r0 + r) * C + c0 + tc];
  }
  __syncthreads();
#pragma unroll
  for (int i = 0; i < 4; ++i) {
    int rr = tr + i * 8;
    d[(size_t)(c0 + rr) * R + r0 + tc] = f2bf(tile[tc][rr]);
  }
}

// ---------------- zero pad rows of Hpad + zero row N_ of x2bf ---------------
__global__ __launch_bounds__(256) void zero_pad_kernel(uint16_t* Hpad, uint16_t* x2bf) {
  int ib = blockIdx.x, t = threadIdx.x;
  uint16_t* dst;
  if (ib < 60) {
    int b = ib / 30, j = ib % 30;
    int row = b * SP_ + (j < 15 ? j : 2048 + j);
    dst = Hpad + (size_t)row * D_;
  } else {
    dst = x2bf + (size_t)N_ * D_;
  }
  dst[t] = 0;
  dst[t + 256] = 0;
}

// ---------------- LayerNorm -> bf16 (optionally into padded Hpad) -----------
__global__ __launch_bounds__(256) void ln_bf16_kernel(
    const float* __restrict__ in, uint16_t* __restrict__ out,
    const float* __restrict__ scale, const float* __restrict__ bias, int hpad) {
  int row = blockIdx.x;
  const float* xr = in + (size_t)row * D_;
  int t = threadIdx.x;
  float v0 = xr[t], v1 = xr[t + 256];
  float s = v0 + v1, sq = v0 * v0 + v1 * v1;
  for (int o = 32; o > 0; o >>= 1) {
    s += __shfl_down(s, o);
    sq += __shfl_down(sq, o);
  }
  __shared__ float sm[8];
  __shared__ float mr[2];
  int lane = t & 63, wid = t >> 6;
  if (lane == 0) { sm[wid] = s; sm[wid + 4] = sq; }
  __syncthreads();
  if (t == 0) {
    float ts = sm[0] + sm[1] + sm[2] + sm[3];
    float tq = sm[4] + sm[5] + sm[6] + sm[7];
    float m = ts / D_;
    mr[0] = m;
    mr[1] = rsqrtf(tq / D_ - m * m + EPS_);
  }
  __syncthreads();
  float m = mr[0], rs = mr[1];
  size_t drow = hpad ? ((size_t)(row >> 11) * SP_ + 15 + (row & 2047)) : (size_t)row;
  uint16_t* orow = out + drow * D_;
  orow[t] = f2bf((v0 - m) * rs * scale[t] + bias[t]);
  orow[t + 256] = f2bf((v1 - m) * rs * scale[t + 256] + bias[t + 256]);
}

// ---------------- conv as 31 shifted GEMMs, split-K over taps (4 slices) ----
__global__ __launch_bounds__(256) void conv_mfma_kernel(
    const uint16_t* __restrict__ Hpad, const uint16_t* __restrict__ ckT,
    float* __restrict__ Pout) {
  __shared__ __align__(16) uint16_t As[4096], Bs[4096];
  int tm = blockIdx.x, tn = blockIdx.y, ks = blockIdx.z;
  int t = threadIdx.x;
  int w = t >> 6, l = t & 63, l15 = l & 15, k8 = (l >> 4) * 8;
  int wr = w >> 1, wc = w & 1;
  int row0 = tm * 128, b = row0 >> 11, s0 = row0 & 2047;
  f32x4 acc[4][4] = {};
  int kb = ks * 8, ke = (ks == 3) ? 31 : kb + 8;
  for (int k = kb; k < ke; ++k) {
    const uint16_t* Ak = Hpad + (size_t)(b * SP_ + s0 + k) * D_;
    const uint16_t* Bk = ckT + (size_t)k * D_ * D_ + (size_t)(tn * 128) * D_;
    for (int d0 = 0; d0 < D_; d0 += 32) {
      stage_pair(Ak + d0, D_, Bk + d0, D_, t, As, Bs);
      SYNC_STAGE();
      kstep_compute(As, Bs, wr, wc, l15, k8, acc);
      __syncthreads();
    }
  }
  float* P = Pout + (size_t)ks * N_ * D_;
#pragma unroll
  for (int m = 0; m < 4; ++m) {
    int r = row0 + wr * 64 + m * 16 + (l >> 4) * 4;
#pragma unroll
    for (int n = 0; n < 4; ++n) {
      int c = tn * 128 + wc * 64 + n * 16 + l15;
#pragma unroll
      for (int j = 0; j < 4; ++j)
        P[(size_t)(r + j) * D_ + c] = acc[m][n][j];
    }
  }
}

// ---------------- conv epilogue: x1 = gelu(P0+P1+P2+P3 + cb) + x ------------
__global__ __launch_bounds__(256) void conv_epi_kernel(
    const float* __restrict__ P, const float* __restrict__ cb,
    const float* __restrict__ xres, float* __restrict__ x1) {
  int idx = blockIdx.x * 256 + threadIdx.x;
  const float4* p0 = (const float4*)P;
  const float4* p1 = (const float4*)(P + (size_t)N_ * D_);
  const float4* p2 = (const float4*)(P + (size_t)2 * N_ * D_);
  const float4* p3 = (const float4*)(P + (size_t)3 * N_ * D_);
  float4 a = p0[idx], b = p1[idx], c = p2[idx], d = p3[idx];
  float4 bias = *(const float4*)(cb + ((idx * 4) & (D_ - 1)));
  float4 r = ((const float4*)xres)[idx];
  float4 o;
  o.x = gelu_f(a.x + b.x + c.x + d.x + bias.x) + r.x;
  o.y = gelu_f(a.y + b.y + c.y + d.y + bias.y) + r.y;
  o.z = gelu_f(a.z + b.z + c.z + d.z + bias.z) + r.z;
  o.w = gelu_f(a.w + b.w + c.w + d.w + bias.w) + r.w;
  ((float4*)x1)[idx] = o;
}

// ------- fused QKV GEMM -> bf16 Q(scaled 1/8), K, V ------------------------
__global__ __launch_bounds__(256) void gemm_qkv_kernel(
    const uint16_t* __restrict__ A, const uint16_t* __restrict__ BT,
    const float* __restrict__ bq, const float* __restrict__ bk,
    const float* __restrict__ bv, uint16_t* __restrict__ Qb,
    uint16_t* __restrict__ Kb, uint16_t* __restrict__ Vb) {
  __shared__ __align__(16) uint16_t As[4096], Bs[4096];
  int tm = blockIdx.x, tn = blockIdx.y;
  int t = threadIdx.x;
  int w = t >> 6, l = t & 63, l15 = l & 15, k8 = (l >> 4) * 8;
  int wr = w >> 1, wc = w & 1;
  int row0 = tm * 128;
  f32x4 acc[4][4] = {};
  const uint16_t* Ab = A + (size_t)row0 * D_;
  const uint16_t* Bb = BT + (size_t)(tn * 128) * D_;
  for (int k0 = 0; k0 < D_; k0 += 32) {
    stage_pair(Ab + k0, D_, Bb + k0, D_, t, As, Bs);
    SYNC_STAGE();
    kstep_compute(As, Bs, wr, wc, l15, k8, acc);
    __syncthreads();
  }
  int sel = tn >> 2, col0 = (tn & 3) * 128;
  uint16_t* dst = sel == 0 ? Qb : (sel == 1 ? Kb : Vb);
  const float* bias = sel == 0 ? bq : (sel == 1 ? bk : bv);
  float scl = sel == 0 ? 0.125f : 1.0f;
#pragma unroll
  for (int m = 0; m < 4; ++m) {
    int r = row0 + wr * 64 + m * 16 + (l >> 4) * 4;
#pragma unroll
    for (int n = 0; n < 4; ++n) {
      int c = col0 + wc * 64 + n * 16 + l15;
#pragma unroll
      for (int j = 0; j < 4; ++j)
        dst[(size_t)(r + j) * D_ + c] = f2bf((acc[m][n][j] + bias[c]) * scl);
    }
  }
}

// ---------------- WO GEMM + bias + residual -> out (f32) + x2 (bf16) --------
__global__ __launch_bounds__(256) void gemm_wo_kernel(
    const uint16_t* __restrict__ A, const uint16_t* __restrict__ BT,
    const float* __restrict__ bo, const float* __restrict__ res,
    float* __restrict__ out, uint16_t* __restrict__ x2bf) {
  __shared__ __align__(16) uint16_t As[4096], Bs[4096];
  int tm = blockIdx.x, tn = blockIdx.y;
  int t = threadIdx.x;
  int w = t >> 6, l = t & 63, l15 = l & 15, k8 = (l >> 4) * 8;
  int wr = w >> 1, wc = w & 1;
  int row0 = tm * 128;
  f32x4 acc[4][4] = {};
  const uint16_t* Ab = A + (size_t)row0 * D_;
  const uint16_t* Bb = BT + (size_t)(tn * 128) * D_;
  for (int k0 = 0; k0 < D_; k0 += 32) {
    stage_pair(Ab + k0, D_, Bb + k0, D_, t, As, Bs);
    SYNC_STAGE();
    kstep_compute(As, Bs, wr, wc, l15, k8, acc);
    __syncthreads();
  }
#pragma unroll
  for (int m = 0; m < 4; ++m) {
    int r = row0 + wr * 64 + m * 16 + (l >> 4) * 4;
#pragma unroll
    for (int n = 0; n < 4; ++n) {
      int c = tn * 128 + wc * 64 + n * 16 + l15;
#pragma unroll
      for (int j = 0; j < 4; ++j) {
        float v = acc[m][n][j] + bo[c] + res[(size_t)(r + j) * D_ + c];
        out[(size_t)(r + j) * D_ + c] = v;
        x2bf[(size_t)(r + j) * D_ + c] = f2bf(v);
      }
    }
  }
}

// ---------------- MFMA flash attention -------------------------------------
// Block: 64 q-rows, 4 waves x 16 q each; K-tiles of 64 keys.
// All LDS tiles 128B rows with XOR swizzle byte ^= ((row&7)<<4):
//   Ks staged via global_load_lds with source-preswizzle,
//   Vt (V transposed) + Plds reg-written swizzled.
__global__ __launch_bounds__(256) void attn_mfma_kernel(
    const uint16_t* __restrict__ Qbf, const uint16_t* __restrict__ Kbf,
    const uint16_t* __restrict__ Vbf, uint16_t* __restrict__ obf) {
  __shared__ __align__(16) uint16_t Ks[4096];   // [64 key][64 d] swizzled
  __shared__ __align__(16) uint16_t Vt[4096];   // [64 d][64 key] swizzled
  __shared__ __align__(16) uint16_t Plds[4096]; // per-wave [16 q][64 key] swizzled
  int qt = blockIdx.x, h = blockIdx.y, b = blockIdx.z;
  int t = threadIdx.x, w = t >> 6, l = t & 63;
  int l15 = l & 15, g = l >> 4;
  int qbase = b * S_ + qt * 64;
  // Q fragments in registers (Q pre-scaled by 1/8 in qkv epilogue)
  bf16x8 qa[2];
  {
    const uint16_t* qp = Qbf + (size_t)(qbase + w * 16 + l15) * D_ + h * HD_;
#pragma unroll
    for (int ks = 0; ks < 2; ++ks)
      qa[ks] = *(const bf16x8*)(qp + ks * 32 + g * 8);
  }
  f32x4 acc_o[4] = {};
  float m_run[4], l_run[4];
#pragma unroll
  for (int j = 0; j < 4; ++j) { m_run[j] = -INFINITY; l_run[j] = 0.f; }
  char* Pw = (char*)Plds + w * 2048;

  for (int kt = 0; kt < S_ / 64; ++kt) {
    __syncthreads();  // previous tile fully consumed
    // --- stage K (global_load_lds, source-preswizzled) ---
    {
      int c0 = t, c1 = t + 256;
      int r0 = c0 >> 3, sb0 = ((c0 & 7) * 16) ^ ((r0 & 7) << 4);
      int r1 = c1 >> 3, sb1 = ((c1 & 7) * 16) ^ ((r1 & 7) << 4);
      GLOAD_LDS16((const char*)(Kbf + (size_t)(b * S_ + kt * 64 + r0) * D_ + h * HD_) + sb0,
                  (char*)Ks + (t & ~63) * 16);
      GLOAD_LDS16((const char*)(Kbf + (size_t)(b * S_ + kt * 64 + r1) * D_ + h * HD_) + sb1,
                  (char*)Ks + 4096 + (t & ~63) * 16);
    }
    // --- stage V transposed (reg roundtrip, swizzled writes) ---
    {
      int r = t & 63, dh = t >> 6;
      const uint16_t* vp = Vbf + (size_t)(b * S_ + kt * 64 + r) * D_ + h * HD_ + dh * 16;
      u16x8 v0 = *(const u16x8*)vp;
      u16x8 v1 = *(const u16x8*)(vp + 8);
#pragma unroll
      for (int i = 0; i < 8; ++i) {
        int d = dh * 16 + i;
        *(uint16_t*)((char*)Vt + ((d * 128 + r * 2) ^ ((d & 7) << 4))) = v0[i];
      }
#pragma unroll
      for (int i = 0; i < 8; ++i) {
        int d = dh * 16 + 8 + i;
        *(uint16_t*)((char*)Vt + ((d * 128 + r * 2) ^ ((d & 7) << 4))) = v1[i];
      }
    }
    SYNC_STAGE();
    // --- S = Q K^T (16 q x 64 k per wave) ---
    f32x4 accs[4] = {};
#pragma unroll
    for (int ks = 0; ks < 2; ++ks) {
#pragma unroll
      for (int n = 0; n < 4; ++n) {
        int row = n * 16 + l15;
        bf16x8 kb = *(const bf16x8*)((const char*)Ks +
                        ((row * 128 + ks * 64 + g * 16) ^ ((row & 7) << 4)));
        accs[n] = __builtin_amdgcn_mfma_f32_16x16x32_bf16(qa[ks], kb, accs[n], 0, 0, 0);
      }
    }
    // --- online softmax (rows spread over 16 lanes: xor 1,2,4,8) ---
    float corr[4];
#pragma unroll
    for (int j = 0; j < 4; ++j) {
      float m0 = fmaxf(fmaxf(accs[0][j], accs[1][j]), fmaxf(accs[2][j], accs[3][j]));
      for (int o_ = 1; o_ < 16; o_ <<= 1) m0 = fmaxf(m0, __shfl_xor(m0, o_));
      float mnew = fmaxf(m_run[j], m0);
      corr[j] = __expf(m_run[j] - mnew);
      m_run[j] = mnew;
    }
    float rsum[4] = {0.f, 0.f, 0.f, 0.f};
#pragma unroll
    for (int n = 0; n < 4; ++n) {
#pragma unroll
      for (int j = 0; j < 4; ++j) {
        float p = __expf(accs[n][j] - m_run[j]);
        rsum[j] += p;
        int row = g * 4 + j, col = n * 16 + l15;
        *(uint16_t*)(Pw + ((row * 128 + col * 2) ^ ((row & 7) << 4))) = f2bf(p);
      }
    }
#pragma unroll
    for (int j = 0; j < 4; ++j) {
      float s = rsum[j];
      for (int o_ = 1; o_ < 16; o_ <<= 1) s += __shfl_xor(s, o_);
      l_run[j] = l_run[j] * corr[j] + s;
#pragma unroll
      for (int n = 0; n < 4; ++n) acc_o[n][j] *= corr[j];
    }
    // --- O += P V ---
#pragma unroll
    for (int ks = 0; ks < 2; ++ks) {
      bf16x8 pa = *(const bf16x8*)(Pw +
                      ((l15 * 128 + ks * 64 + g * 16) ^ ((l15 & 7) << 4)));
#pragma unroll
      for (int n = 0; n < 4; ++n) {
        int d = n * 16 + l15;
        bf16x8 vb = *(const bf16x8*)((const char*)Vt +
                        ((d * 128 + ks * 64 + g * 16) ^ ((d & 7) << 4)));
        acc_o[n] = __builtin_amdgcn_mfma_f32_16x16x32_bf16(pa, vb, acc_o[n], 0, 0, 0);
      }
    }
  }
#pragma unroll
  for (int j = 0; j < 4; ++j) {
    float inv = 1.f / l_run[j];
    uint16_t* op = obf + (size_t)(qbase + w * 16 + g * 4 + j) * D_ + h * HD_;
#pragma unroll
    for (int n = 0; n < 4; ++n)
      op[n * 16 + l15] = f2bf(acc_o[n][j] * inv);
  }
}

// ---------------- MoE bucketing: group tokens, pad to 128 -------------------
__global__ __launch_bounds__(1024) void bucket_kernel(
    const int* __restrict__ gid, int* __restrict__ list, int* __restrict__ poff) {
  __shared__ int cnt[G_], cur[G_];
  int t = threadIdx.x;
  if (t < G_) cnt[t] = 0;
  __syncthreads();
  for (int i = t; i < N_; i += 1024) atomicAdd(&cnt[gid[i]], 1);
  __syncthreads();
  if (t == 0) {
    int off = 0;
    for (int g = 0; g < G_; ++g) {
      poff[g] = off;
      cur[g] = off;
      off += (cnt[g] + 127) & ~127;
    }
    poff[G_] = off;
  }
  __syncthreads();
  for (int i = t; i < PADCAP_; i += 1024) list[i] = N_;
  __syncthreads();
  for (int i = t; i < N_; i += 1024) {
    int p = atomicAdd(&cur[gid[i]], 1);
    list[p] = i;
  }
}

// ---------------- MoE FF1 (gathered A), both experts via grid.z -------------
__global__ __launch_bounds__(256) void ff1_mfma_kernel(
    const uint16_t* __restrict__ X, const uint16_t* __restrict__ w1T,
    const float* __restrict__ b1, const int* __restrict__ list,
    const int* __restrict__ poff, uint16_t* __restrict__ hid) {
  __shared__ __align__(16) uint16_t As[4096], Bs[4096];
  int tm = blockIdx.x, tn = blockIdx.y, e = blockIdx.z;
  int slot0 = tm * 128;
  if (slot0 >= poff[G_]) return;
  int g = 0;
#pragma unroll
  for (int gg = 1; gg < G_; ++gg) g += (slot0 >= poff[gg]);
  int t = threadIdx.x;
  int w = t >> 6, l = t & 63, l15 = l & 15, k8 = (l >> 4) * 8;
  int wr = w >> 1, wc = w & 1;
  int tokA = list[slot0 + (t >> 2)];
  int tokB = list[slot0 + 64 + (t >> 2)];
  int col = (t & 3) * 8, uoff = (t & ~63) * 8;
  f32x4 acc[4][4] = {};
  const uint16_t* Bb = w1T + ((size_t)(g * E_ + e) * FF_ + tn * 128) * D_;
  for (int k0 = 0; k0 < D_; k0 += 32) {
    GLOAD_LDS16(X + (size_t)tokA * D_ + k0 + col, As + uoff);
    GLOAD_LDS16(X + (size_t)tokB * D_ + k0 + col, As + 2048 + uoff);
    int row = t >> 2;
    GLOAD_LDS16(Bb + (size_t)row * D_ + k0 + col, Bs + uoff);
    GLOAD_LDS16(Bb + (size_t)(row + 64) * D_ + k0 + col, Bs + 2048 + uoff);
    SYNC_STAGE();
    kstep_compute(As, Bs, wr, wc, l15, k8, acc);
    __syncthreads();
  }
  const float* bias = b1 + (size_t)(g * E_ + e) * FF_;
  uint16_t* hidE = hid + (size_t)e * PADCAP_ * FF_;
#pragma unroll
  for (int m = 0; m < 4; ++m) {
    int r = slot0 + wr * 64 + m * 16 + (l >> 4) * 4;
#pragma unroll
    for (int n = 0; n < 4; ++n) {
      int c = tn * 128 + wc * 64 + n * 16 + l15;
#pragma unroll
      for (int j = 0; j < 4; ++j)
        hidE[(size_t)(r + j) * FF_ + c] = f2bf(gelu_f(acc[m][n][j] + bias[c]));
    }
  }
}

// ---------------- MoE FF2: both experts accumulated, scatter-add to out -----
__global__ __launch_bounds__(256) void ff2_mfma_kernel(
    const uint16_t* __restrict__ hid, const uint16_t* __restrict__ w2T,
    const float* __restrict__ b2, const int* __restrict__ list,
    const int* __restrict__ poff, float* __restrict__ out) {
  __shared__ __align__(16) uint16_t As[4096], Bs[4096];
  int tm = blockIdx.x, tn = blockIdx.y;
  int slot0 = tm * 128;
  if (slot0 >= poff[G_]) return;
  int g = 0;
#pragma unroll
  for (int gg = 1; gg < G_; ++gg) g += (slot0 >= poff[gg]);
  int t = threadIdx.x;
  int w = t >> 6, l = t & 63, l15 = l & 15, k8 = (l >> 4) * 8;
  int wr = w >> 1, wc = w & 1;
  f32x4 acc[4][4] = {};
  for (int e = 0; e < E_; ++e) {
    const uint16_t* Ab = hid + (size_t)e * PADCAP_ * FF_ + (size_t)slot0 * FF_;
    const uint16_t* Bb = w2T + (size_t)(g * E_ + e) * D_ * FF_ + (size_t)(tn * 128) * FF_;
    for (int k0 = 0; k0 < FF_; k0 += 32) {
      stage_pair(Ab + k0, FF_, Bb + k0, FF_, t, As, Bs);
      SYNC_STAGE();
      kstep_compute(As, Bs, wr, wc, l15, k8, acc);
      __syncthreads();
    }
  }
  const float* b2a = b2 + (size_t)(g * E_) * D_;
  const float* b2b = b2 + (size_t)(g * E_ + 1) * D_;
#pragma unroll
  for (int m = 0; m < 4; ++m) {
    int rbase = slot0 + wr * 64 + m * 16 + (l >> 4) * 4;
#pragma unroll
    for (int j = 0; j < 4; ++j) {
      int tok = list[rbase + j];
      if (tok >= N_) continue;
#pragma unroll
      for (int n = 0; n < 4; ++n) {
        int c = tn * 128 + wc * 64 + n * 16 + l15;
        out[(size_t)tok * D_ + c] += 0.5f * (acc[m][n][j] + b2a[c] + b2b[c]);
      }
    }
  }
}

}  // namespace

extern "C" void kernel_launch(void* const* d_in, const int* in_sizes, int n_in,
                              void* d_out, int out_size, void* d_ws, size_t ws_size,
                              hipStream_t stream) {
  const float* x = (const float*)d_in[0];
  const int* gid = (const int*)d_in[1];
  const float* ln1s = (const float*)d_in[2];
  const float* ln1b = (const float*)d_in[3];
  const float* ck = (const float*)d_in[4];
  const float* cb = (const float*)d_in[5];
  const float* ln2s = (const float*)d_in[6];
  const float* ln2b = (const float*)d_in[7];
  const float* wq = (const float*)d_in[8];
  const float* bq = (const float*)d_in[9];
  const float* wk = (const float*)d_in[10];
  const float* bk = (const float*)d_in[11];
  const float* wv = (const float*)d_in[12];
  const float* bv = (const float*)d_in[13];
  const float* wo = (const float*)d_in[14];
  const float* bo = (const float*)d_in[15];
  const float* w1 = (const float*)d_in[16];
  const float* b1 = (const float*)d_in[17];
  const float* w2 = (const float*)d_in[18];
  const float* b2 = (const float*)d_in[19];
  float* out = (float*)d_out;

  char* ws = (char*)d_ws;
  // Region A (38 MiB), time-multiplexed:
  //  conv:  P[4] f32 partials (32 MiB)
  //  attn:  ln2bf(4) | Qbf(4) | Kbf(4) | Vbf(4) | obf(4)   [bf16]
  //  moe:   hidbf (36 MiB)
  char* A = ws;
  float* P = (float*)A;
  uint16_t* ln2bf = (uint16_t*)A;
  uint16_t* Qbf = (uint16_t*)(A + (4ull << 20));
  uint16_t* Kbf = (uint16_t*)(A + (8ull << 20));
  uint16_t* Vbf = (uint16_t*)(A + (12ull << 20));
  uint16_t* obf = (uint16_t*)(A + (16ull << 20));
  uint16_t* hidbf = (uint16_t*)A;

  float* x1 = (float*)(ws + (38ull << 20));
  uint16_t* Hpad = (uint16_t*)(ws + (46ull << 20));
  uint16_t* ckT = (uint16_t*)(ws + (51ull << 20));
  uint16_t* wqkvT = (uint16_t*)(ws + (67ull << 20));
  uint16_t* woT = (uint16_t*)(ws + (69ull << 20));
  uint16_t* w1T = (uint16_t*)(ws + (70ull << 20));
  uint16_t* w2T = (uint16_t*)(ws + (86ull << 20));
  uint16_t* x2bf = (uint16_t*)(ws + (102ull << 20));
  int* list = (int*)(ws + (107ull << 20));
  int* poff = list + PADCAP_;

  transpose_bf16_kernel<<<dim3(16, 16, 31), 256, 0, stream>>>(ck, ckT, 512, 512);
  transpose_bf16_kernel<<<dim3(16, 16, 1), 256, 0, stream>>>(wq, wqkvT, 512, 512);
  transpose_bf16_kernel<<<dim3(16, 16, 1), 256, 0, stream>>>(wk, wqkvT + 512 * 512, 512, 512);
  transpose_bf16_kernel<<<dim3(16, 16, 1), 256, 0, stream>>>(wv, wqkvT + 2 * 512 * 512, 512, 512);
  transpose_bf16_kernel<<<dim3(16, 16, 1), 256, 0, stream>>>(wo, woT, 512, 512);
  transpose_bf16_kernel<<<dim3(64, 16, 8), 256, 0, stream>>>(w1, w1T, 512, 2048);
  transpose_bf16_kernel<<<dim3(16, 64, 8), 256, 0, stream>>>(w2, w2T, 2048, 512);
  zero_pad_kernel<<<61, 256, 0, stream>>>(Hpad, x2bf);
  bucket_kernel<<<1, 1024, 0, stream>>>(gid, list, poff);

  // conv sublayer
  ln_bf16_kernel<<<N_, 256, 0, stream>>>(x, Hpad, ln1s, ln1b, 1);
  conv_mfma_kernel<<<dim3(32, 4, 4), 256, 0, stream>>>(Hpad, ckT, P);
  conv_epi_kernel<<<2048, 256, 0, stream>>>(P, cb, x, x1);

  // attention sublayer
  ln_bf16_kernel<<<N_, 256, 0, stream>>>(x1, ln2bf, ln2s, ln2b, 0);
  gemm_qkv_kernel<<<dim3(32, 12), 256, 0, stream>>>(ln2bf, wqkvT, bq, bk, bv, Qbf, Kbf, Vbf);
  attn_mfma_kernel<<<dim3(S_ / 64, H_, B_), 256, 0, stream>>>(Qbf, Kbf, Vbf, obf);
  gemm_wo_kernel<<<dim3(32, 4), 256, 0, stream>>>(obf, woT, bo, x1, out, x2bf);

  // MoE sublayer
  ff1_mfma_kernel<<<dim3(36, 16, 2), 256, 0, stream>>>(x2bf, w1T, b1, list, poff, hidbf);
  ff2_mfma_kernel<<<dim3(36, 4), 256, 0, stream>>>(hidbf, w2T, b2, list, poff, out);
}